// Round 7
// baseline (182.663 us; speedup 1.0000x reference)
//
#include <hip/hip_runtime.h>

// Problem constants (fixed by setup_inputs)
constexpr int Bn = 128, Cn = 3, Sn = 256;
constexpr int HWn = Sn * Sn;          // 65536
constexpr int NPLANE = Bn * Cn;       // 384
constexpr float DTf = 0.05f;
constexpr float EPSf = 1e-6f;
constexpr float MAXCf = 1.0f;

// ws float layout:
//   [8..25]        r[step][dir][c] (18)
//   [32..127]      means partials (6 groups x 16 blocks)
//   [128..4735]    cp tables [18][256] (cp[255] = TRUE value)
//   [4736..9343]   dinv tables [18][256]
//   [9344..13951]  cdy: y-dir (cp,dinv) float2 [9][256]  (index = step*3+c)
#define WS_R    8
#define WS_PART 32
#define WS_CP   128
#define WS_DINV 4736
#define WS_CDY  9344

__global__ void means_part(const float* __restrict__ aspat,
                           const float* __restrict__ bspat,
                           float* __restrict__ ws) {
  int grp = blockIdx.x >> 4;   // 0..5 = dir*3 + c
  int sub = blockIdx.x & 15;
  const float* base = (grp < 3) ? (aspat + grp * HWn) : (bspat + (grp - 3) * HWn);
  const float4* p = (const float4*)base + sub * 1024 + threadIdx.x;
  double acc = 0.0;
#pragma unroll
  for (int k = 0; k < 4; ++k) {
    float4 v = p[k * 256];
    acc += (double)v.x + (double)v.y + (double)v.z + (double)v.w;
  }
  __shared__ double sm[256];
  sm[threadIdx.x] = acc;
  __syncthreads();
  for (int s = 128; s > 0; s >>= 1) {
    if (threadIdx.x < s) sm[threadIdx.x] += sm[threadIdx.x + s];
    __syncthreads();
  }
  if (threadIdx.x == 0) ws[WS_PART + blockIdx.x] = (float)sm[0];
}

// One thread per (step, dir, channel): build cp[256], dinv[256] (+ interleaved
// y-table), r.
__global__ void coeff_kernel(const float* __restrict__ alpha_base,
                             const float* __restrict__ beta_base,
                             float* __restrict__ ws) {
  int id = threadIdx.x;
  if (id >= 18) return;
  int s = id / 6, dir = (id / 3) % 2, c = id % 3;
  double msum = 0.0;
  for (int k = 0; k < 16; ++k) msum += (double)ws[WS_PART + (dir * 3 + c) * 16 + k];
  float mean = (float)(msum * (1.0 / HWn));
  float t = (float)s * DTf;
  float base = (dir == 0) ? alpha_base[c] : beta_base[c];
  float coef = fminf(fmaxf(base + mean * t, EPSf), MAXCf);
  float r = coef * (DTf * 0.5f);  // DX = 1
  ws[WS_R + id] = r;
  float* cp = ws + WS_CP + id * 256;
  float* dinv = ws + WS_DINV + id * 256;
  float2* cdy = (float2*)(ws + WS_CDY) + (s * 3 + c) * 256;  // used iff dir==1
  float b0 = 1.0f + r;
  float bi = 1.0f + 2.0f * r;
  dinv[0] = 1.0f / (b0 + EPSf);
  cp[0] = -r / (b0 + EPSf);
  if (dir == 1) cdy[0] = make_float2(cp[0], dinv[0]);
  for (int i = 1; i < 256; ++i) {
    float b = (i == 255) ? b0 : bi;
    float denom = fmaxf(b + r * cp[i - 1], EPSf);  // b - a*cp_prev, a=-r
    cp[i] = -r / denom;
    dinv[i] = 1.0f / denom;
    if (dir == 1) cdy[i] = make_float2(cp[i], dinv[i]);
  }
  // cp[255] TRUE: forward uses -cp[i]==r*dinv[i] at all i; back-substitution
  // never multiplies cp[255] (x_top = dp_top explicitly).
}

// ------------- Fully-fused kernel: 3 ADI steps (6 solves) in one pass -------
// Block = (plane, stripe): W-row x 256-col LDS window (W=88 interior, 76
// edges), core 64 rows. Halo 4 per y-solve per truncated side (trunc err
// ~0.0075^5 ~ 1e-11). diag applied to the field at the END of EVERY step.
// LDS swizzle (involution, quad-granular): (rl,col) at word
//   rl*256 + ((colq ^ (rl&7))<<2 | col&3).
// Coefficients are read via wave-uniform scalar loads from ws (K$-resident);
// no LDS tables.
__global__ __launch_bounds__(512, 2) void fused3(
    const float* __restrict__ src, float* __restrict__ dst,
    const float* __restrict__ ws, const float* __restrict__ coupling) {
  __shared__ float tile[88 * 256];           // 90112 B
  const int t = threadIdx.x;
  // XCD-bijective swizzle: 1536 = 8*192; same-plane stripes -> same XCD.
  const int logical = (blockIdx.x & 7) * 192 + (blockIdx.x >> 3);
  const int plane = logical >> 2;            // b*3 + c
  const int s = logical & 3;                 // stripe
  const int c = plane % 3;

  const int a0 = (s == 0) ? 0 : ((s == 3) ? 180 : 64 * s - 12);
  const int W = (s == 0 || s == 3) ? 76 : 88;

  // ---- DMA all W rows (linear LDS dest, inverse-swizzled global source) ----
  {
    const int wv = t >> 6, l = t & 63;
    const float* srcp = src + (size_t)plane * HWn;
#pragma unroll
    for (int kk = 0; kk < 11; ++kk) {
      const int rl = wv * 11 + kk;
      if (rl < W) {
        const float* gp = srcp + (size_t)(a0 + rl) * 256 + ((l ^ (rl & 7)) << 2);
        __builtin_amdgcn_global_load_lds(
            (const __attribute__((address_space(1))) void*)gp,
            (__attribute__((address_space(3))) void*)(tile + rl * 256), 16, 0, 0);
      }
    }
  }
  const float dg = coupling[c * 3 + c];      // uniform scalar load
  asm volatile("s_waitcnt vmcnt(0)" ::: "memory");
  __syncthreads();

  for (int k = 0; k < 3; ++k) {
    // ====== x-solve: 4 wave-uniform col-chunks/row, 18-quad windows ======
    {
      const int wvu = __builtin_amdgcn_readfirstlane(t >> 6);
      const int cw = wvu >> 1;                      // wave-uniform chunk
      const int rw = (wvu & 1) * 64 + (t & 63);
      const int qs = (cw == 0) ? 0 : (cw == 1) ? 15 : (cw == 2) ? 31 : 46;
      const int off = (cw == 0) ? 0 : (cw == 3) ? 2 : 1;  // core rel [off,off+16)
      const bool act = rw < W;
      const float4* __restrict__ cpx =
          (const float4*)(ws + WS_CP + (size_t)(6 * k + c) * 256) + qs;
      const float4* __restrict__ dix =
          (const float4*)(ws + WS_DINV + (size_t)(6 * k + c) * 256) + qs;
      float4* trow = (float4*)tile + rw * 64;
      const int sw = rw & 7;
      float4 dq[18];
      if (act) {
        float prev = 0.0f;                   // exact at col 0 (cw0); trunc else
#pragma unroll
        for (int i = 0; i < 18; ++i) {
          const int q = qs + i;
          const float4 v = trow[q ^ sw];
          const float4 cq = cpx[i];
          const float4 eq = dix[i];
          float d0 = fmaf(-cq.x, prev, v.x * eq.x);
          float d1 = fmaf(-cq.y, d0, v.y * eq.y);
          float d2 = fmaf(-cq.z, d1, v.z * eq.z);
          float d3 = fmaf(-cq.w, d2, v.w * eq.w);
          dq[i] = make_float4(d0, d1, d2, d3);
          prev = d3;
        }
      }
      __syncthreads();                       // all fwd halo-reads before writes
      if (act) {
        float x = 0.0f;
#pragma unroll
        for (int i = 17; i >= 0; --i) {
          const int q = qs + i;
          const float4 cq = cpx[i];
          const float4 v = dq[i];
          float x3 = (i == 17) ? v.w : fmaf(-cq.w, x, v.w);
          float x2 = fmaf(-cq.z, x3, v.z);
          float x1 = fmaf(-cq.y, x2, v.y);
          float x0 = fmaf(-cq.x, x1, v.x);
          if (i >= off && i < off + 16) trow[q ^ sw] = make_float4(x0, x1, x2, x3);
          x = x0;
        }
      }
      __syncthreads();
    }
    // ====== y-solve: 4 segs x 128 col-pairs, uniform 48-row windows ======
    {
      const int segu = __builtin_amdgcn_readfirstlane(t >> 7);
      const int pair = t & 127;
      const int j0 = 2 * pair;
      const int vlo = (s == 0) ? 0 : 4 * k;
      const int vhi = (s == 3) ? 76 : W - 4 * k;
      const int olo = (s == 0) ? 0 : 4 * (k + 1);
      const int ohi = (s == 3) ? 76 : W - 4 * (k + 1);
      const int olen = (ohi - olo) >> 2;
      const int out_lo = olo + segu * olen;
      int hs = out_lo - 4;
      if (hs < vlo) hs = vlo;
      if (hs > vhi - 48) hs = vhi - 48;
      const int wlo = out_lo - hs, whi = wlo + olen;
      const float2* __restrict__ cdp =
          (const float2*)(ws + WS_CDY) + (size_t)(3 * k + c) * 256 + (a0 + hs);
      const int jq = pair >> 1;
      const int jin = (pair & 1) * 2;
      float* bp[8];
#pragma unroll
      for (int p = 0; p < 8; ++p) {
        const int rl = hs + p;
        bp[p] = tile + rl * 256 + (((jq ^ (rl & 7)) << 2) | jin);
      }
      float2 dp[48];
      float px = 0.0f, py = 0.0f;            // exact at global row 0; trunc else
#pragma unroll
      for (int o = 0; o < 6; ++o) {
#pragma unroll
        for (int p = 0; p < 8; ++p) {
          const int i = 8 * o + p;
          const float2 cd = cdp[i];          // scalar (SGPR) loads
          const float2 v = *(const float2*)(bp[p] + o * 2048);
          px = fmaf(-cd.x, px, v.x * cd.y);
          py = fmaf(-cd.x, py, v.y * cd.y);
          dp[i] = make_float2(px, py);
        }
      }
      __syncthreads();                       // all fwd reads before bwd writes
      float xx = 0.0f, xy = 0.0f;
      if (k == 2) {
        float* dstp = dst + (size_t)plane * HWn + (size_t)(a0 + hs) * 256 + j0;
#pragma unroll
        for (int i = 47; i >= 0; --i) {
          if (i == 47) { xx = dp[47].x; xy = dp[47].y; }
          else {
            const float cpi = cdp[i].x;
            xx = fmaf(-cpi, xx, dp[i].x);
            xy = fmaf(-cpi, xy, dp[i].y);
          }
          if (i >= wlo && i < whi)
            *(float2*)(dstp + (size_t)i * 256) = make_float2(xx * dg, xy * dg);
        }
      } else {
#pragma unroll
        for (int o = 5; o >= 0; --o) {
#pragma unroll
          for (int p = 7; p >= 0; --p) {
            const int i = 8 * o + p;
            if (i == 47) { xx = dp[47].x; xy = dp[47].y; }
            else {
              const float cpi = cdp[i].x;
              xx = fmaf(-cpi, xx, dp[i].x);
              xy = fmaf(-cpi, xy, dp[i].y);
            }
            if (i >= wlo && i < whi)
              *(float2*)(bp[p] + o * 2048) = make_float2(xx * dg, xy * dg);
          }
        }
        __syncthreads();
      }
    }
  }
}

extern "C" void kernel_launch(void* const* d_in, const int* in_sizes, int n_in,
                              void* d_out, int out_size, void* d_ws, size_t ws_size,
                              hipStream_t stream) {
  const float* u = (const float*)d_in[0];
  const float* alpha_base = (const float*)d_in[1];
  const float* beta_base = (const float*)d_in[2];
  const float* alpha_spatial = (const float*)d_in[3];
  const float* beta_spatial = (const float*)d_in[4];
  const float* coupling = (const float*)d_in[5];
  float* out = (float*)d_out;
  float* ws = (float*)d_ws;

  means_part<<<96, 256, 0, stream>>>(alpha_spatial, beta_spatial, ws);
  coeff_kernel<<<1, 64, 0, stream>>>(alpha_base, beta_base, ws);
  fused3<<<NPLANE * 4, 512, 0, stream>>>(u, out, ws, coupling);
}

// Round 8
// 150.578 us; speedup vs baseline: 1.2131x; 1.2131x over previous
//
#include <hip/hip_runtime.h>

// Problem constants (fixed by setup_inputs)
constexpr int Bn = 128, Cn = 3, Sn = 256;
constexpr int HWn = Sn * Sn;          // 65536
constexpr int NPLANE = Bn * Cn;       // 384
constexpr float DTf = 0.05f;
constexpr float EPSf = 1e-6f;
constexpr float MAXCf = 1.0f;

// ws float layout:
//   [8..25]        r[step][dir][c] (18)
//   [32..127]      means partials (6 groups x 16 blocks)
//   [128..4735]    cp tables [18][256] (cp[255] = TRUE value)
//   [4736..9343]   dinv tables [18][256]
//   [9344..13951]  cdy: y-dir (cp,dinv) float2 [9][256]  (index = step*3+c)
#define WS_R    8
#define WS_PART 32
#define WS_CP   128
#define WS_DINV 4736
#define WS_CDY  9344

__global__ void means_part(const float* __restrict__ aspat,
                           const float* __restrict__ bspat,
                           float* __restrict__ ws) {
  int grp = blockIdx.x >> 4;   // 0..5 = dir*3 + c
  int sub = blockIdx.x & 15;
  const float* base = (grp < 3) ? (aspat + grp * HWn) : (bspat + (grp - 3) * HWn);
  const float4* p = (const float4*)base + sub * 1024 + threadIdx.x;
  double acc = 0.0;
#pragma unroll
  for (int k = 0; k < 4; ++k) {
    float4 v = p[k * 256];
    acc += (double)v.x + (double)v.y + (double)v.z + (double)v.w;
  }
  __shared__ double sm[256];
  sm[threadIdx.x] = acc;
  __syncthreads();
  for (int s = 128; s > 0; s >>= 1) {
    if (threadIdx.x < s) sm[threadIdx.x] += sm[threadIdx.x + s];
    __syncthreads();
  }
  if (threadIdx.x == 0) ws[WS_PART + blockIdx.x] = (float)sm[0];
}

// One thread per (step, dir, channel): build cp[256], dinv[256] (+ interleaved
// y-table), r.
__global__ void coeff_kernel(const float* __restrict__ alpha_base,
                             const float* __restrict__ beta_base,
                             float* __restrict__ ws) {
  int id = threadIdx.x;
  if (id >= 18) return;
  int s = id / 6, dir = (id / 3) % 2, c = id % 3;
  double msum = 0.0;
  for (int k = 0; k < 16; ++k) msum += (double)ws[WS_PART + (dir * 3 + c) * 16 + k];
  float mean = (float)(msum * (1.0 / HWn));
  float t = (float)s * DTf;
  float base = (dir == 0) ? alpha_base[c] : beta_base[c];
  float coef = fminf(fmaxf(base + mean * t, EPSf), MAXCf);
  float r = coef * (DTf * 0.5f);  // DX = 1
  ws[WS_R + id] = r;
  float* cp = ws + WS_CP + id * 256;
  float* dinv = ws + WS_DINV + id * 256;
  float2* cdy = (float2*)(ws + WS_CDY) + (s * 3 + c) * 256;  // used iff dir==1
  float b0 = 1.0f + r;
  float bi = 1.0f + 2.0f * r;
  dinv[0] = 1.0f / (b0 + EPSf);
  cp[0] = -r / (b0 + EPSf);
  if (dir == 1) cdy[0] = make_float2(cp[0], dinv[0]);
  for (int i = 1; i < 256; ++i) {
    float b = (i == 255) ? b0 : bi;
    float denom = fmaxf(b + r * cp[i - 1], EPSf);  // b - a*cp_prev, a=-r
    cp[i] = -r / denom;
    dinv[i] = 1.0f / denom;
    if (dir == 1) cdy[i] = make_float2(cp[i], dinv[i]);
  }
  // cp[255] TRUE: forward uses -cp[i]==r*dinv[i] at all i; back-substitution
  // never multiplies cp[255] (x_top = dp_top explicitly).
}

// ------------- Fully-fused kernel: 3 ADI steps (6 solves) in one pass -------
// Block = (plane, stripe): W-row x 256-col LDS window (W=76 interior, 70
// edges), core 64 rows. Halo 2 rows per y-solve per truncated side (local
// trunc err ~7.6e-3*0.0076^2 ~ 4e-7, attenuated by diag^remaining ~ 5e-11 at
// output). diag applied to the field at the END of EVERY step.
// LDS swizzle (involution, quad-granular): (rl,col) at word
//   rl*256 + ((colq ^ (rl&7))<<2 | col&3).
// Coefficients via wave-uniform scalar loads from ws (K$); no LDS tables.
// Tile 77824 B <= 80 KiB -> 2 blocks/CU (16 waves/CU).
__global__ __launch_bounds__(512, 4) void fused3(
    const float* __restrict__ src, float* __restrict__ dst,
    const float* __restrict__ ws, const float* __restrict__ coupling) {
  __shared__ float tile[76 * 256];           // 77824 B
  const int t = threadIdx.x;
  // XCD-bijective swizzle: 1536 = 8*192; same-plane stripes -> same XCD.
  const int logical = (blockIdx.x & 7) * 192 + (blockIdx.x >> 3);
  const int plane = logical >> 2;            // b*3 + c
  const int s = logical & 3;                 // stripe
  const int c = plane % 3;

  const int a0 = (s == 0) ? 0 : ((s == 3) ? 186 : 64 * s - 6);
  const int W = (s == 0 || s == 3) ? 70 : 76;

  // ---- DMA all W rows (linear LDS dest, inverse-swizzled global source) ----
  {
    const int wv = t >> 6, l = t & 63;
    const float* srcp = src + (size_t)plane * HWn;
#pragma unroll
    for (int kk = 0; kk < 10; ++kk) {
      const int rl = wv * 10 + kk;
      if (rl < W) {
        const float* gp = srcp + (size_t)(a0 + rl) * 256 + ((l ^ (rl & 7)) << 2);
        __builtin_amdgcn_global_load_lds(
            (const __attribute__((address_space(1))) void*)gp,
            (__attribute__((address_space(3))) void*)(tile + rl * 256), 16, 0, 0);
      }
    }
  }
  const float dg = coupling[c * 3 + c];      // uniform scalar load
  asm volatile("s_waitcnt vmcnt(0)" ::: "memory");
  __syncthreads();

  for (int k = 0; k < 3; ++k) {
    // ====== x-solve: 4 wave-uniform col-chunks/row, 18-quad windows ======
    {
      const int wvu = __builtin_amdgcn_readfirstlane(t >> 6);
      const int cw = wvu >> 1;                      // wave-uniform chunk
      const int rw = (wvu & 1) * 64 + (t & 63);
      const int qs = (cw == 0) ? 0 : (cw == 1) ? 15 : (cw == 2) ? 31 : 46;
      const int off = (cw == 0) ? 0 : (cw == 3) ? 2 : 1;  // core rel [off,off+16)
      const bool act = rw < W;
      const float4* __restrict__ cpx =
          (const float4*)(ws + WS_CP + (size_t)(6 * k + c) * 256) + qs;
      const float4* __restrict__ dix =
          (const float4*)(ws + WS_DINV + (size_t)(6 * k + c) * 256) + qs;
      float4* trow = (float4*)tile + rw * 64;
      const int sw = rw & 7;
      float4 dq[18];
      if (act) {
        float prev = 0.0f;                   // exact at col 0 (cw0); trunc else
#pragma unroll
        for (int i = 0; i < 18; ++i) {
          const int q = qs + i;
          const float4 v = trow[q ^ sw];
          const float4 cq = cpx[i];
          const float4 eq = dix[i];
          float d0 = fmaf(-cq.x, prev, v.x * eq.x);
          float d1 = fmaf(-cq.y, d0, v.y * eq.y);
          float d2 = fmaf(-cq.z, d1, v.z * eq.z);
          float d3 = fmaf(-cq.w, d2, v.w * eq.w);
          dq[i] = make_float4(d0, d1, d2, d3);
          prev = d3;
        }
      }
      __syncthreads();                       // all fwd halo-reads before writes
      if (act) {
        float x = 0.0f;
#pragma unroll
        for (int i = 17; i >= 0; --i) {
          const int q = qs + i;
          const float4 cq = cpx[i];
          const float4 v = dq[i];
          float x3 = (i == 17) ? v.w : fmaf(-cq.w, x, v.w);
          float x2 = fmaf(-cq.z, x3, v.z);
          float x1 = fmaf(-cq.y, x2, v.y);
          float x0 = fmaf(-cq.x, x1, v.x);
          if (i >= off && i < off + 16) trow[q ^ sw] = make_float4(x0, x1, x2, x3);
          x = x0;
        }
      }
      __syncthreads();
    }
    // ====== y-solve: 4 segs x 128 col-pairs, tight 24-row windows ======
    {
      const int segu = __builtin_amdgcn_readfirstlane(t >> 7);
      const int pair = t & 127;
      const int j0 = 2 * pair;
      const int vlo = (s == 0) ? 0 : 2 * k;            // valid band
      const int vhi = (s == 3) ? W : W - 2 * k;
      const int olo = (s == 0) ? 0 : 2 * (k + 1);      // output band
      const int ohi = (s == 3) ? W : W - 2 * (k + 1);
      const int olen = (ohi - olo + 3) >> 2;
      const int out_lo = olo + segu * olen;
      int out_hi = out_lo + olen; if (out_hi > ohi) out_hi = ohi;
      int hs = out_lo - 2;
      if (hs < vlo) hs = vlo;
      if (hs > vhi - 24) hs = vhi - 24;
      const int wlo = out_lo - hs, whi = out_hi - hs;
      const float2* __restrict__ cdp =
          (const float2*)(ws + WS_CDY) + (size_t)(3 * k + c) * 256 + (a0 + hs);
      const int jq = pair >> 1;
      const int jin = (pair & 1) * 2;
      float* bp[8];
#pragma unroll
      for (int p = 0; p < 8; ++p) {
        const int rl = hs + p;
        bp[p] = tile + rl * 256 + (((jq ^ (rl & 7)) << 2) | jin);
      }
      float2 dp[24];
      float px = 0.0f, py = 0.0f;            // exact at global row 0; trunc else
#pragma unroll
      for (int o = 0; o < 3; ++o) {
#pragma unroll
        for (int p = 0; p < 8; ++p) {
          const int i = 8 * o + p;
          const float2 cd = cdp[i];          // scalar (SGPR) loads
          const float2 v = *(const float2*)(bp[p] + o * 2048);
          px = fmaf(-cd.x, px, v.x * cd.y);
          py = fmaf(-cd.x, py, v.y * cd.y);
          dp[i] = make_float2(px, py);
        }
      }
      __syncthreads();                       // all fwd reads before bwd writes
      float xx = 0.0f, xy = 0.0f;
      if (k == 2) {
        float* dstp = dst + (size_t)plane * HWn + (size_t)(a0 + hs) * 256 + j0;
#pragma unroll
        for (int i = 23; i >= 0; --i) {
          if (i == 23) { xx = dp[23].x; xy = dp[23].y; }
          else {
            const float cpi = cdp[i].x;
            xx = fmaf(-cpi, xx, dp[i].x);
            xy = fmaf(-cpi, xy, dp[i].y);
          }
          if (i >= wlo && i < whi)
            *(float2*)(dstp + (size_t)i * 256) = make_float2(xx * dg, xy * dg);
        }
      } else {
#pragma unroll
        for (int o = 2; o >= 0; --o) {
#pragma unroll
          for (int p = 7; p >= 0; --p) {
            const int i = 8 * o + p;
            if (i == 23) { xx = dp[23].x; xy = dp[23].y; }
            else {
              const float cpi = cdp[i].x;
              xx = fmaf(-cpi, xx, dp[i].x);
              xy = fmaf(-cpi, xy, dp[i].y);
            }
            if (i >= wlo && i < whi)
              *(float2*)(bp[p] + o * 2048) = make_float2(xx * dg, xy * dg);
          }
        }
        __syncthreads();
      }
    }
  }
}

extern "C" void kernel_launch(void* const* d_in, const int* in_sizes, int n_in,
                              void* d_out, int out_size, void* d_ws, size_t ws_size,
                              hipStream_t stream) {
  const float* u = (const float*)d_in[0];
  const float* alpha_base = (const float*)d_in[1];
  const float* beta_base = (const float*)d_in[2];
  const float* alpha_spatial = (const float*)d_in[3];
  const float* beta_spatial = (const float*)d_in[4];
  const float* coupling = (const float*)d_in[5];
  float* out = (float*)d_out;
  float* ws = (float*)d_ws;

  means_part<<<96, 256, 0, stream>>>(alpha_spatial, beta_spatial, ws);
  coeff_kernel<<<1, 64, 0, stream>>>(alpha_base, beta_base, ws);
  fused3<<<NPLANE * 4, 512, 0, stream>>>(u, out, ws, coupling);
}